// Round 2
// baseline (477.908 us; speedup 1.0000x reference)
//
#include <hip/hip_runtime.h>
#include <cstdint>
#include <cstddef>

#define IN_F 2048
#define OUT_F 2048
#define BM 128
#define BN 128
#define BK 64

typedef int v4i __attribute__((ext_vector_type(4)));

// ---------------- FWHT(64) across 16 lanes x float4 ----------------
// Element p of the 64-block = (lane&15)*4 + j, block = lane>>4 (4 blocks/wave).
__device__ inline void fwht64(float& a, float& b, float& c, float& d, int lane) {
    float t;
    // p-bit 1 (in-lane j^1)
    t = a; a = t + b; b = t - b;
    t = c; c = t + d; d = t - d;
    // p-bit 2 (in-lane j^2)
    t = a; a = t + c; c = t - c;
    t = b; b = t + d; d = t - d;
    // p-bits 4,8,16,32 -> lane xor 1,2,4,8 (within 16-lane group)
#pragma unroll
    for (int s = 1; s <= 8; s <<= 1) {
        float sg = (lane & s) ? -1.0f : 1.0f;
        float pa = __shfl_xor(a, s), pb = __shfl_xor(b, s);
        float pc = __shfl_xor(c, s), pd = __shfl_xor(d, s);
        a = fmaf(sg, a, pa);
        b = fmaf(sg, b, pb);
        c = fmaf(sg, c, pc);
        d = fmaf(sg, d, pd);
    }
}

__global__ void fwht_absmax_kernel(const float* __restrict__ in, int ngroups,
                                   unsigned int* __restrict__ amax_bits) {
    const int lane = threadIdx.x & 63;
    const int gw = (blockIdx.x * blockDim.x + threadIdx.x) >> 6;
    const int nw = (gridDim.x * blockDim.x) >> 6;
    float m = 0.0f;
    for (int g = gw; g < ngroups; g += nw) {
        float4 v = reinterpret_cast<const float4*>(in)[(size_t)g * 64 + lane];
        fwht64(v.x, v.y, v.z, v.w, lane);
        m = fmaxf(m, fmaxf(fmaxf(fabsf(v.x), fabsf(v.y)),
                           fmaxf(fabsf(v.z), fabsf(v.w))));
    }
    m *= 0.125f;  // 1/sqrt(64), exact power of 2
#pragma unroll
    for (int s = 32; s >= 1; s >>= 1) m = fmaxf(m, __shfl_xor(m, s));
    if (lane == 0) atomicMax(reinterpret_cast<int*>(amax_bits), __float_as_int(m));
}

__global__ void fwht_quant_kernel(const float* __restrict__ in, int ngroups,
                                  const float* __restrict__ amax,
                                  uint32_t* __restrict__ outq) {
    const int lane = threadIdx.x & 63;
    const int gw = (blockIdx.x * blockDim.x + threadIdx.x) >> 6;
    const int nw = (gridDim.x * blockDim.x) >> 6;
    const float scale = fmaxf(*amax / 127.0f, 1.17549435e-38f);
    const float rs = 1.0f / scale;
    for (int g = gw; g < ngroups; g += nw) {
        float4 v = reinterpret_cast<const float4*>(in)[(size_t)g * 64 + lane];
        fwht64(v.x, v.y, v.z, v.w, lane);
        float qa = fminf(fmaxf(rintf(v.x * 0.125f * rs), -127.f), 127.f);
        float qb = fminf(fmaxf(rintf(v.y * 0.125f * rs), -127.f), 127.f);
        float qc = fminf(fmaxf(rintf(v.z * 0.125f * rs), -127.f), 127.f);
        float qd = fminf(fmaxf(rintf(v.w * 0.125f * rs), -127.f), 127.f);
        uint32_t pk = ((uint32_t)((int)qa & 0xff)) |
                      ((uint32_t)((int)qb & 0xff) << 8) |
                      ((uint32_t)((int)qc & 0xff) << 16) |
                      ((uint32_t)((int)qd & 0xff) << 24);
        outq[(size_t)g * 64 + lane] = pk;
    }
}

// ---------------- int8 GEMM: out[M,N] = (Aq[M,K] . Bq[N,K]^T) * f + bias ----------------
__global__ __launch_bounds__(256, 2) void gemm_i8_kernel(
    const int8_t* __restrict__ Aq, const int8_t* __restrict__ Bq,
    const float* __restrict__ scales, const float* __restrict__ bias,
    float* __restrict__ out, int M) {
    __shared__ int8_t sA[BM * BK];
    __shared__ int8_t sB[BN * BK];
    const int tid = threadIdx.x;
    const int lane = tid & 63;
    const int wave = tid >> 6;
    const int wr = wave >> 1, wc = wave & 1;
    const int nbn = OUT_F / BN;  // 16

    // XCD-aware swizzle (grid % 8 == 0)
    int nwg = gridDim.x;
    int cpx = nwg >> 3;
    int bid = (blockIdx.x & 7) * cpx + (blockIdx.x >> 3);
    const int bm0 = (bid / nbn) * BM;
    const int bn0 = (bid % nbn) * BN;

    const int l15 = lane & 15;
    const int lseg = lane >> 4;

    v4i acc[4][4] = {};

    for (int kk = 0; kk < IN_F; kk += BK) {
#pragma unroll
        for (int i = 0; i < 2; ++i) {
            int off = tid * 16 + i * 4096;
            int row = off >> 6, col = off & 63;
            __builtin_amdgcn_global_load_lds(
                (const __attribute__((address_space(1))) void*)(Aq + (size_t)(bm0 + row) * IN_F + kk + col),
                (__attribute__((address_space(3))) void*)(sA + off), 16, 0, 0);
            __builtin_amdgcn_global_load_lds(
                (const __attribute__((address_space(1))) void*)(Bq + (size_t)(bn0 + row) * IN_F + kk + col),
                (__attribute__((address_space(3))) void*)(sB + off), 16, 0, 0);
        }
        __syncthreads();

        v4i af[4], bf[4];
#pragma unroll
        for (int mi = 0; mi < 4; ++mi)
            af[mi] = *reinterpret_cast<const v4i*>(sA + (wr * 64 + mi * 16 + l15) * 64 + lseg * 16);
#pragma unroll
        for (int ni = 0; ni < 4; ++ni)
            bf[ni] = *reinterpret_cast<const v4i*>(sB + (wc * 64 + ni * 16 + l15) * 64 + lseg * 16);

#pragma unroll
        for (int mi = 0; mi < 4; ++mi)
#pragma unroll
            for (int ni = 0; ni < 4; ++ni)
                acc[mi][ni] = __builtin_amdgcn_mfma_i32_16x16x64_i8(af[mi], bf[ni], acc[mi][ni], 0, 0, 0);
        __syncthreads();
    }

    const float sx = fmaxf(scales[0] / 127.0f, 1.17549435e-38f);
    const float sw = fmaxf(scales[1] / 127.0f, 1.17549435e-38f);
    const float f = sx * sw;

#pragma unroll
    for (int mi = 0; mi < 4; ++mi) {
#pragma unroll
        for (int ni = 0; ni < 4; ++ni) {
            const int col = bn0 + wc * 64 + ni * 16 + l15;
            const float bcol = bias[col];
#pragma unroll
            for (int r = 0; r < 4; ++r) {
                const int row = bm0 + wr * 64 + mi * 16 + lseg * 4 + r;
                out[(size_t)row * OUT_F + col] = (float)acc[mi][ni][r] * f + bcol;
            }
        }
    }
}

extern "C" void kernel_launch(void* const* d_in, const int* in_sizes, int n_in,
                              void* d_out, int out_size, void* d_ws, size_t ws_size,
                              hipStream_t stream) {
    const float* x = (const float*)d_in[0];
    const float* w = (const float*)d_in[1];
    const float* bias = (const float*)d_in[2];
    const int xN = in_sizes[0];       // M * IN_F
    const int wN = in_sizes[1];       // OUT_F * IN_F
    const int M = xN / IN_F;

    uint8_t* ws8 = (uint8_t*)d_ws;
    unsigned int* amax = (unsigned int*)d_ws;   // [0]=x absmax bits, [1]=w absmax bits
    float* scales = (float*)d_ws;
    uint32_t* xq = (uint32_t*)(ws8 + 64);
    uint32_t* wq = (uint32_t*)(ws8 + 64 + (size_t)xN);

    hipMemsetAsync(d_ws, 0, 64, stream);

    const int xg = xN / 256;
    const int wg = wN / 256;
    hipLaunchKernelGGL(fwht_absmax_kernel, dim3(2048), dim3(256), 0, stream, x, xg, amax + 0);
    hipLaunchKernelGGL(fwht_absmax_kernel, dim3(1024), dim3(256), 0, stream, w, wg, amax + 1);
    hipLaunchKernelGGL(fwht_quant_kernel, dim3(2048), dim3(256), 0, stream, x, xg, scales + 0, xq);
    hipLaunchKernelGGL(fwht_quant_kernel, dim3(1024), dim3(256), 0, stream, w, wg, scales + 1, wq);

    const int nwg = (M / BM) * (OUT_F / BN);
    hipLaunchKernelGGL(gemm_i8_kernel, dim3(nwg), dim3(256), 0, stream,
                       (const int8_t*)xq, (const int8_t*)wq, scales, bias, (float*)d_out, M);
}

// Round 5
// 356.425 us; speedup vs baseline: 1.3408x; 1.3408x over previous
//
#include <hip/hip_runtime.h>
#include <cstdint>
#include <cstddef>

#define IN_F 2048
#define OUT_F 2048
#define BM 128
#define BN 128
#define BK 64

typedef int v4i __attribute__((ext_vector_type(4)));

// ---------------- FWHT(64) across 16 lanes x float4 ----------------
// Element p of the 64-block = (lane&15)*4 + j, block = lane>>4 (4 blocks/wave).
__device__ inline void fwht64(float& a, float& b, float& c, float& d, int lane) {
    float t;
    t = a; a = t + b; b = t - b;
    t = c; c = t + d; d = t - d;
    t = a; a = t + c; c = t - c;
    t = b; b = t + d; d = t - d;
#pragma unroll
    for (int s = 1; s <= 8; s <<= 1) {
        float sg = (lane & s) ? -1.0f : 1.0f;
        float pa = __shfl_xor(a, s), pb = __shfl_xor(b, s);
        float pc = __shfl_xor(c, s), pd = __shfl_xor(d, s);
        a = fmaf(sg, a, pa);
        b = fmaf(sg, b, pb);
        c = fmaf(sg, c, pc);
        d = fmaf(sg, d, pd);
    }
}

__global__ void fwht_absmax_kernel(const float* __restrict__ in, int ngroups,
                                   float* __restrict__ partials) {
    const int lane = threadIdx.x & 63;
    const int wave = threadIdx.x >> 6;
    const int gw = (blockIdx.x * blockDim.x + threadIdx.x) >> 6;
    const int nw = (gridDim.x * blockDim.x) >> 6;
    float m = 0.0f;
    for (int g = gw; g < ngroups; g += nw) {
        float4 v = reinterpret_cast<const float4*>(in)[(size_t)g * 64 + lane];
        fwht64(v.x, v.y, v.z, v.w, lane);
        m = fmaxf(m, fmaxf(fmaxf(fabsf(v.x), fabsf(v.y)),
                           fmaxf(fabsf(v.z), fabsf(v.w))));
    }
    m *= 0.125f;  // 1/sqrt(64), exact power of 2
#pragma unroll
    for (int s = 32; s >= 1; s >>= 1) m = fmaxf(m, __shfl_xor(m, s));
    __shared__ float sm[4];
    if (lane == 0) sm[wave] = m;
    __syncthreads();
    if (threadIdx.x == 0)
        partials[blockIdx.x] = fmaxf(fmaxf(sm[0], sm[1]), fmaxf(sm[2], sm[3]));
}

__global__ void reduce_scales_kernel(const float* __restrict__ partX, int nX,
                                     const float* __restrict__ partW, int nW,
                                     float* __restrict__ scales) {
    const int tid = threadIdx.x;
    const int lane = tid & 63;
    const int wave = tid >> 6;
    float mx = 0.0f, mw = 0.0f;
    for (int i = tid; i < nX; i += 256) mx = fmaxf(mx, partX[i]);
    for (int i = tid; i < nW; i += 256) mw = fmaxf(mw, partW[i]);
#pragma unroll
    for (int s = 32; s >= 1; s >>= 1) {
        mx = fmaxf(mx, __shfl_xor(mx, s));
        mw = fmaxf(mw, __shfl_xor(mw, s));
    }
    __shared__ float smx[4], smw[4];
    if (lane == 0) { smx[wave] = mx; smw[wave] = mw; }
    __syncthreads();
    if (tid == 0) {
        scales[0] = fmaxf(fmaxf(smx[0], smx[1]), fmaxf(smx[2], smx[3]));
        scales[1] = fmaxf(fmaxf(smw[0], smw[1]), fmaxf(smw[2], smw[3]));
    }
}

__global__ void fwht_quant_kernel(const float* __restrict__ in, int ngroups,
                                  const float* __restrict__ amax,
                                  uint32_t* __restrict__ outq) {
    const int lane = threadIdx.x & 63;
    const int gw = (blockIdx.x * blockDim.x + threadIdx.x) >> 6;
    const int nw = (gridDim.x * blockDim.x) >> 6;
    const float scale = fmaxf(*amax / 127.0f, 1.17549435e-38f);
    const float rs = 1.0f / scale;
    for (int g = gw; g < ngroups; g += nw) {
        float4 v = reinterpret_cast<const float4*>(in)[(size_t)g * 64 + lane];
        fwht64(v.x, v.y, v.z, v.w, lane);
        float qa = fminf(fmaxf(rintf(v.x * 0.125f * rs), -127.f), 127.f);
        float qb = fminf(fmaxf(rintf(v.y * 0.125f * rs), -127.f), 127.f);
        float qc = fminf(fmaxf(rintf(v.z * 0.125f * rs), -127.f), 127.f);
        float qd = fminf(fmaxf(rintf(v.w * 0.125f * rs), -127.f), 127.f);
        uint32_t pk = ((uint32_t)((int)qa & 0xff)) |
                      ((uint32_t)((int)qb & 0xff) << 8) |
                      ((uint32_t)((int)qc & 0xff) << 16) |
                      ((uint32_t)((int)qd & 0xff) << 24);
        outq[(size_t)g * 64 + lane] = pk;
    }
}

// ---------------- int8 GEMM: out[M,N] = (Aq[M,K] . Bq[N,K]^T) * f + bias ----------------
// 2-phase double-buffered: stage(t+1) issued before compute(t), one barrier/tile.
__global__ __launch_bounds__(256, 2) void gemm_i8_kernel(
    const int8_t* __restrict__ Aq, const int8_t* __restrict__ Bq,
    const float* __restrict__ scales, const float* __restrict__ bias,
    float* __restrict__ out, int M) {
    __shared__ int8_t sA[2][BM * BK];
    __shared__ int8_t sB[2][BN * BK];
    const int tid = threadIdx.x;
    const int lane = tid & 63;
    const int wave = tid >> 6;
    const int wr = wave >> 1, wc = wave & 1;
    const int nbn = OUT_F / BN;  // 16

    // XCD-aware swizzle (grid % 8 == 0)
    int nwg = gridDim.x;
    int cpx = nwg >> 3;
    int bid = (blockIdx.x & 7) * cpx + (blockIdx.x >> 3);
    const int bm0 = (bid / nbn) * BM;
    const int bn0 = (bid % nbn) * BN;

    const int l15 = lane & 15;
    const int lseg = lane >> 4;

    // staging coordinates (fixed per thread)
    const int soff0 = tid * 16;
    const int soff1 = tid * 16 + 4096;
    const int srow0 = soff0 >> 6, scol0 = soff0 & 63;
    const int srow1 = soff1 >> 6, scol1 = soff1 & 63;
    const int8_t* gA0 = Aq + (size_t)(bm0 + srow0) * IN_F + scol0;
    const int8_t* gA1 = Aq + (size_t)(bm0 + srow1) * IN_F + scol1;
    const int8_t* gB0 = Bq + (size_t)(bn0 + srow0) * IN_F + scol0;
    const int8_t* gB1 = Bq + (size_t)(bn0 + srow1) * IN_F + scol1;

#define STAGE(buf, kk)                                                                   \
    do {                                                                                 \
        __builtin_amdgcn_global_load_lds(                                                \
            (const __attribute__((address_space(1))) void*)(gA0 + (kk)),                 \
            (__attribute__((address_space(3))) void*)(&sA[buf][soff0]), 16, 0, 0);       \
        __builtin_amdgcn_global_load_lds(                                                \
            (const __attribute__((address_space(1))) void*)(gA1 + (kk)),                 \
            (__attribute__((address_space(3))) void*)(&sA[buf][soff1]), 16, 0, 0);       \
        __builtin_amdgcn_global_load_lds(                                                \
            (const __attribute__((address_space(1))) void*)(gB0 + (kk)),                 \
            (__attribute__((address_space(3))) void*)(&sB[buf][soff0]), 16, 0, 0);       \
        __builtin_amdgcn_global_load_lds(                                                \
            (const __attribute__((address_space(1))) void*)(gB1 + (kk)),                 \
            (__attribute__((address_space(3))) void*)(&sB[buf][soff1]), 16, 0, 0);       \
    } while (0)

    v4i acc[4][4] = {};

    STAGE(0, 0);
    __syncthreads();

    int cur = 0;
    for (int kk = BK; kk < IN_F; kk += BK) {
        STAGE(cur ^ 1, kk);

        v4i af[4], bf[4];
#pragma unroll
        for (int mi = 0; mi < 4; ++mi)
            af[mi] = *reinterpret_cast<const v4i*>(&sA[cur][(wr * 64 + mi * 16 + l15) * 64 + lseg * 16]);
#pragma unroll
        for (int ni = 0; ni < 4; ++ni)
            bf[ni] = *reinterpret_cast<const v4i*>(&sB[cur][(wc * 64 + ni * 16 + l15) * 64 + lseg * 16]);

#pragma unroll
        for (int mi = 0; mi < 4; ++mi)
#pragma unroll
            for (int ni = 0; ni < 4; ++ni)
                acc[mi][ni] = __builtin_amdgcn_mfma_i32_16x16x64_i8(af[mi], bf[ni], acc[mi][ni], 0, 0, 0);

        __syncthreads();  // drains vmcnt(0): next buffer ready; all reads of cur done
        cur ^= 1;
    }

    {  // final tile
        v4i af[4], bf[4];
#pragma unroll
        for (int mi = 0; mi < 4; ++mi)
            af[mi] = *reinterpret_cast<const v4i*>(&sA[cur][(wr * 64 + mi * 16 + l15) * 64 + lseg * 16]);
#pragma unroll
        for (int ni = 0; ni < 4; ++ni)
            bf[ni] = *reinterpret_cast<const v4i*>(&sB[cur][(wc * 64 + ni * 16 + l15) * 64 + lseg * 16]);
#pragma unroll
        for (int mi = 0; mi < 4; ++mi)
#pragma unroll
            for (int ni = 0; ni < 4; ++ni)
                acc[mi][ni] = __builtin_amdgcn_mfma_i32_16x16x64_i8(af[mi], bf[ni], acc[mi][ni], 0, 0, 0);
    }
#undef STAGE

    const float sx = fmaxf(scales[0] / 127.0f, 1.17549435e-38f);
    const float sw = fmaxf(scales[1] / 127.0f, 1.17549435e-38f);
    const float f = sx * sw;

#pragma unroll
    for (int mi = 0; mi < 4; ++mi) {
#pragma unroll
        for (int ni = 0; ni < 4; ++ni) {
            const int col = bn0 + wc * 64 + ni * 16 + l15;
            const float bcol = bias[col];
#pragma unroll
            for (int r = 0; r < 4; ++r) {
                const int row = bm0 + wr * 64 + mi * 16 + lseg * 4 + r;
                out[(size_t)row * OUT_F + col] = (float)acc[mi][ni][r] * f + bcol;
            }
        }
    }
}

extern "C" void kernel_launch(void* const* d_in, const int* in_sizes, int n_in,
                              void* d_out, int out_size, void* d_ws, size_t ws_size,
                              hipStream_t stream) {
    const float* x = (const float*)d_in[0];
    const float* w = (const float*)d_in[1];
    const float* bias = (const float*)d_in[2];
    const int xN = in_sizes[0];       // M * IN_F
    const int wN = in_sizes[1];       // OUT_F * IN_F
    const int M = xN / IN_F;

    uint8_t* ws8 = (uint8_t*)d_ws;
    float* scales = (float*)ws8;                       // [0]=x absmax, [1]=w absmax
    float* partX = (float*)(ws8 + 256);                // 2048 floats
    float* partW = (float*)(ws8 + 256 + 8192);         // 1024 floats
    uint32_t* xq = (uint32_t*)(ws8 + 16384);
    uint32_t* wq = (uint32_t*)(ws8 + 16384 + (size_t)xN);

    const int xg = xN / 256;
    const int wg = wN / 256;
    const int GX = 2048, GW = 1024;
    hipLaunchKernelGGL(fwht_absmax_kernel, dim3(GX), dim3(256), 0, stream, x, xg, partX);
    hipLaunchKernelGGL(fwht_absmax_kernel, dim3(GW), dim3(256), 0, stream, w, wg, partW);
    hipLaunchKernelGGL(reduce_scales_kernel, dim3(1), dim3(256), 0, stream, partX, GX, partW, GW, scales);
    hipLaunchKernelGGL(fwht_quant_kernel, dim3(2048), dim3(256), 0, stream, x, xg, scales + 0, xq);
    hipLaunchKernelGGL(fwht_quant_kernel, dim3(1024), dim3(256), 0, stream, w, wg, scales + 1, wq);

    const int nwg = (M / BM) * (OUT_F / BN);
    hipLaunchKernelGGL(gemm_i8_kernel, dim3(nwg), dim3(256), 0, stream,
                       (const int8_t*)xq, (const int8_t*)wq, scales, bias, (float*)d_out, M);
}

// Round 7
// 351.822 us; speedup vs baseline: 1.3584x; 1.0131x over previous
//
#include <hip/hip_runtime.h>
#include <cstdint>
#include <cstddef>

#define IN_F 2048
#define OUT_F 2048
#define BM 128
#define BN 128
#define BK 64
#define GX 2048
#define GW 1024

typedef int v4i __attribute__((ext_vector_type(4)));

// ---------------- FWHT(64) across 16 lanes x float4 ----------------
// Element p of the 64-block = (lane&15)*4 + j, block = lane>>4 (4 blocks/wave).
__device__ inline void fwht64(float& a, float& b, float& c, float& d, int lane) {
    float t;
    t = a; a = t + b; b = t - b;
    t = c; c = t + d; d = t - d;
    t = a; a = t + c; c = t - c;
    t = b; b = t + d; d = t - d;
#pragma unroll
    for (int s = 1; s <= 8; s <<= 1) {
        float sg = (lane & s) ? -1.0f : 1.0f;
        float pa = __shfl_xor(a, s), pb = __shfl_xor(b, s);
        float pc = __shfl_xor(c, s), pd = __shfl_xor(d, s);
        a = fmaf(sg, a, pa);
        b = fmaf(sg, b, pb);
        c = fmaf(sg, c, pc);
        d = fmaf(sg, d, pd);
    }
}

// Merged absmax over x (blocks [0,GX)) and w (blocks [GX,GX+GW)).
__global__ void fwht_absmax_kernel(const float* __restrict__ xin, int xg,
                                   const float* __restrict__ win, int wgn,
                                   float* __restrict__ partials) {
    const int lane = threadIdx.x & 63;
    const int wave = threadIdx.x >> 6;
    const bool isX = blockIdx.x < GX;
    const float* __restrict__ in = isX ? xin : win;
    const int ng = isX ? xg : wgn;
    const int b = isX ? blockIdx.x : blockIdx.x - GX;
    const int nblk = isX ? GX : GW;
    const int gw = (b * blockDim.x + threadIdx.x) >> 6;
    const int nw = (nblk * blockDim.x) >> 6;
    float m = 0.0f;
    for (int g = gw; g < ng; g += nw) {
        float4 v = reinterpret_cast<const float4*>(in)[(size_t)g * 64 + lane];
        fwht64(v.x, v.y, v.z, v.w, lane);
        m = fmaxf(m, fmaxf(fmaxf(fabsf(v.x), fabsf(v.y)),
                           fmaxf(fabsf(v.z), fabsf(v.w))));
    }
    m *= 0.125f;  // 1/sqrt(64), exact power of 2
#pragma unroll
    for (int s = 32; s >= 1; s >>= 1) m = fmaxf(m, __shfl_xor(m, s));
    __shared__ float sm[4];
    if (lane == 0) sm[wave] = m;
    __syncthreads();
    if (threadIdx.x == 0)
        partials[blockIdx.x] = fmaxf(fmaxf(sm[0], sm[1]), fmaxf(sm[2], sm[3]));
}

__global__ void reduce_scales_kernel(const float* __restrict__ partX, int nX,
                                     const float* __restrict__ partW, int nW,
                                     float* __restrict__ scales) {
    const int tid = threadIdx.x;
    const int lane = tid & 63;
    const int wave = tid >> 6;
    float mx = 0.0f, mw = 0.0f;
    for (int i = tid; i < nX; i += 256) mx = fmaxf(mx, partX[i]);
    for (int i = tid; i < nW; i += 256) mw = fmaxf(mw, partW[i]);
#pragma unroll
    for (int s = 32; s >= 1; s >>= 1) {
        mx = fmaxf(mx, __shfl_xor(mx, s));
        mw = fmaxf(mw, __shfl_xor(mw, s));
    }
    __shared__ float smx[4], smw[4];
    if (lane == 0) { smx[wave] = mx; smw[wave] = mw; }
    __syncthreads();
    if (tid == 0) {
        scales[0] = fmaxf(fmaxf(smx[0], smx[1]), fmaxf(smx[2], smx[3]));
        scales[1] = fmaxf(fmaxf(smw[0], smw[1]), fmaxf(smw[2], smw[3]));
    }
}

// Merged quantize: x (blocks [0,GX)) and w (blocks [GX,GX+GW)).
__global__ void fwht_quant_kernel(const float* __restrict__ xin, int xg,
                                  const float* __restrict__ win, int wgn,
                                  const float* __restrict__ scales,
                                  uint32_t* __restrict__ xq, uint32_t* __restrict__ wq) {
    const int lane = threadIdx.x & 63;
    const bool isX = blockIdx.x < GX;
    const float* __restrict__ in = isX ? xin : win;
    uint32_t* __restrict__ outq = isX ? xq : wq;
    const int ng = isX ? xg : wgn;
    const int b = isX ? blockIdx.x : blockIdx.x - GX;
    const int nblk = isX ? GX : GW;
    const int gw = (b * blockDim.x + threadIdx.x) >> 6;
    const int nw = (nblk * blockDim.x) >> 6;
    const float scale = fmaxf(scales[isX ? 0 : 1] / 127.0f, 1.17549435e-38f);
    const float rs = 1.0f / scale;
    for (int g = gw; g < ng; g += nw) {
        float4 v = reinterpret_cast<const float4*>(in)[(size_t)g * 64 + lane];
        fwht64(v.x, v.y, v.z, v.w, lane);
        float qa = fminf(fmaxf(rintf(v.x * 0.125f * rs), -127.f), 127.f);
        float qb = fminf(fmaxf(rintf(v.y * 0.125f * rs), -127.f), 127.f);
        float qc = fminf(fmaxf(rintf(v.z * 0.125f * rs), -127.f), 127.f);
        float qd = fminf(fmaxf(rintf(v.w * 0.125f * rs), -127.f), 127.f);
        uint32_t pk = ((uint32_t)((int)qa & 0xff)) |
                      ((uint32_t)((int)qb & 0xff) << 8) |
                      ((uint32_t)((int)qc & 0xff) << 16) |
                      ((uint32_t)((int)qd & 0xff) << 24);
        outq[(size_t)g * 64 + lane] = pk;
    }
}

// ---------------- int8 GEMM: out[M,N] = (Aq[M,K] . Bq[N,K]^T) * f + bias ----------------
// 2-phase double-buffer + paired-row XOR-swizzled LDS (conflict-free ds_read_b128).
// LDS physical geometry per matrix: [64 pair-rows][128 B]. Logical (m, c16):
//   lrow = m>>1; sl = (m&1)*4 + c16; s = sl ^ (lrow&7); off = lrow*128 + s*16.
// global_load_lds writes linearly, so the per-lane GLOBAL source is inverse-permuted
// and fragment reads apply the same swizzle (both-sides rule).
__global__ __launch_bounds__(256, 2) void gemm_i8_kernel(
    const int8_t* __restrict__ Aq, const int8_t* __restrict__ Bq,
    const float* __restrict__ scales, const float* __restrict__ bias,
    float* __restrict__ out, int M) {
    __shared__ int8_t sA[2][BM * BK];
    __shared__ int8_t sB[2][BN * BK];
    const int tid = threadIdx.x;
    const int lane = tid & 63;
    const int wave = tid >> 6;
    const int wr = wave >> 1, wc = wave & 1;
    const int nbn = OUT_F / BN;  // 16

    // XCD-aware swizzle (grid % 8 == 0)
    int nwg = gridDim.x;
    int cpx = nwg >> 3;
    int bid = (blockIdx.x & 7) * cpx + (blockIdx.x >> 3);
    const int bm0 = (bid / nbn) * BM;
    const int bn0 = (bid % nbn) * BN;

    const int l15 = lane & 15;
    const int lseg = lane >> 4;

    // --- staging: dest off -> inverse-swizzled global (row, col) ---
    const int soff0 = tid * 16;
    const int soff1 = tid * 16 + 4096;
    int lr0 = soff0 >> 7, s0 = (soff0 >> 4) & 7, sl0 = s0 ^ (lr0 & 7);
    int lr1 = soff1 >> 7, s1 = (soff1 >> 4) & 7, sl1 = s1 ^ (lr1 & 7);
    const int m0 = (lr0 << 1) | (sl0 >> 2), c0 = (sl0 & 3) * 16;
    const int m1 = (lr1 << 1) | (sl1 >> 2), c1 = (sl1 & 3) * 16;
    const int8_t* gA0 = Aq + (size_t)(bm0 + m0) * IN_F + c0;
    const int8_t* gA1 = Aq + (size_t)(bm0 + m1) * IN_F + c1;
    const int8_t* gB0 = Bq + (size_t)(bn0 + m0) * IN_F + c0;
    const int8_t* gB1 = Bq + (size_t)(bn0 + m1) * IN_F + c1;

#define STAGE(buf, kk)                                                                   \
    do {                                                                                 \
        __builtin_amdgcn_global_load_lds(                                                \
            (const __attribute__((address_space(1))) void*)(gA0 + (kk)),                 \
            (__attribute__((address_space(3))) void*)(&sA[buf][soff0]), 16, 0, 0);       \
        __builtin_amdgcn_global_load_lds(                                                \
            (const __attribute__((address_space(1))) void*)(gA1 + (kk)),                 \
            (__attribute__((address_space(3))) void*)(&sA[buf][soff1]), 16, 0, 0);       \
        __builtin_amdgcn_global_load_lds(                                                \
            (const __attribute__((address_space(1))) void*)(gB0 + (kk)),                 \
            (__attribute__((address_space(3))) void*)(&sB[buf][soff0]), 16, 0, 0);       \
        __builtin_amdgcn_global_load_lds(                                                \
            (const __attribute__((address_space(1))) void*)(gB1 + (kk)),                 \
            (__attribute__((address_space(3))) void*)(&sB[buf][soff1]), 16, 0, 0);       \
    } while (0)

    // --- fragment read offsets (swizzled), per-thread constants ---
    int offA[4], offB[4];
#pragma unroll
    for (int mi = 0; mi < 4; ++mi) {
        int rowA = wr * 64 + mi * 16 + l15;
        int slA = ((rowA & 1) << 2) | lseg;
        offA[mi] = (rowA >> 1) * 128 + (slA ^ ((rowA >> 1) & 7)) * 16;
        int rowB = wc * 64 + mi * 16 + l15;
        int slB = ((rowB & 1) << 2) | lseg;
        offB[mi] = (rowB >> 1) * 128 + (slB ^ ((rowB >> 1) & 7)) * 16;
    }

    v4i acc[4][4] = {};

    STAGE(0, 0);
    __syncthreads();

    int cur = 0;
    for (int kk = BK; kk < IN_F; kk += BK) {
        STAGE(cur ^ 1, kk);

        v4i af[4], bf[4];
#pragma unroll
        for (int mi = 0; mi < 4; ++mi)
            af[mi] = *reinterpret_cast<const v4i*>(&sA[cur][offA[mi]]);
#pragma unroll
        for (int ni = 0; ni < 4; ++ni)
            bf[ni] = *reinterpret_cast<const v4i*>(&sB[cur][offB[ni]]);

#pragma unroll
        for (int mi = 0; mi < 4; ++mi)
#pragma unroll
            for (int ni = 0; ni < 4; ++ni)
                acc[mi][ni] = __builtin_amdgcn_mfma_i32_16x16x64_i8(af[mi], bf[ni], acc[mi][ni], 0, 0, 0);

        __syncthreads();  // drains vmcnt(0): next buffer ready; all reads of cur done
        cur ^= 1;
    }

    {  // final tile
        v4i af[4], bf[4];
#pragma unroll
        for (int mi = 0; mi < 4; ++mi)
            af[mi] = *reinterpret_cast<const v4i*>(&sA[cur][offA[mi]]);
#pragma unroll
        for (int ni = 0; ni < 4; ++ni)
            bf[ni] = *reinterpret_cast<const v4i*>(&sB[cur][offB[ni]]);
#pragma unroll
        for (int mi = 0; mi < 4; ++mi)
#pragma unroll
            for (int ni = 0; ni < 4; ++ni)
                acc[mi][ni] = __builtin_amdgcn_mfma_i32_16x16x64_i8(af[mi], bf[ni], acc[mi][ni], 0, 0, 0);
    }
#undef STAGE

    const float sx = fmaxf(scales[0] / 127.0f, 1.17549435e-38f);
    const float sw = fmaxf(scales[1] / 127.0f, 1.17549435e-38f);
    const float f = sx * sw;

#pragma unroll
    for (int mi = 0; mi < 4; ++mi) {
#pragma unroll
        for (int ni = 0; ni < 4; ++ni) {
            const int col = bn0 + wc * 64 + ni * 16 + l15;
            const float bcol = bias[col];
#pragma unroll
            for (int r = 0; r < 4; ++r) {
                const int row = bm0 + wr * 64 + mi * 16 + lseg * 4 + r;
                out[(size_t)row * OUT_F + col] = (float)acc[mi][ni][r] * f + bcol;
            }
        }
    }
}

extern "C" void kernel_launch(void* const* d_in, const int* in_sizes, int n_in,
                              void* d_out, int out_size, void* d_ws, size_t ws_size,
                              hipStream_t stream) {
    const float* x = (const float*)d_in[0];
    const float* w = (const float*)d_in[1];
    const float* bias = (const float*)d_in[2];
    const int xN = in_sizes[0];       // M * IN_F
    const int wN = in_sizes[1];       // OUT_F * IN_F
    const int M = xN / IN_F;

    uint8_t* ws8 = (uint8_t*)d_ws;
    float* scales = (float*)ws8;                       // [0]=x absmax, [1]=w absmax
    float* partX = (float*)(ws8 + 256);                // GX floats
    float* partW = partX + GX;                         // GW floats (contiguous)
    uint32_t* xq = (uint32_t*)(ws8 + 16384);
    uint32_t* wq = (uint32_t*)(ws8 + 16384 + (size_t)xN);

    const int xg = xN / 256;
    const int wg = wN / 256;
    hipLaunchKernelGGL(fwht_absmax_kernel, dim3(GX + GW), dim3(256), 0, stream,
                       x, xg, w, wg, partX);
    hipLaunchKernelGGL(reduce_scales_kernel, dim3(1), dim3(256), 0, stream,
                       partX, GX, partW, GW, scales);
    hipLaunchKernelGGL(fwht_quant_kernel, dim3(GX + GW), dim3(256), 0, stream,
                       x, xg, w, wg, scales, xq, wq);

    const int nwg = (M / BM) * (OUT_F / BN);
    hipLaunchKernelGGL(gemm_i8_kernel, dim3(nwg), dim3(256), 0, stream,
                       (const int8_t*)xq, (const int8_t*)wq, scales, bias, (float*)d_out, M);
}